// Round 1
// baseline (90.151 us; speedup 1.0000x reference)
//
#include <hip/hip_runtime.h>

#define NG 3
#define HW 4096
#define NSPOT 32
#define NSPLIT 4
#define PXB (HW / NSPLIT)   // 1024 pixels per block
#define TPB 256
#define PXT (PXB / TPB)     // 4 pixels per thread

// log2(e)/2
#define HALF_LOG2E 0.7213475204444817f
#define LN2 0.6931471805599453f

__device__ __forceinline__ float wave_reduce_sum(float v) {
#pragma unroll
    for (int m = 1; m < 64; m <<= 1) v += __shfl_xor(v, m, 64);
    return v;
}

__global__ __launch_bounds__(TPB) void gmm_main(const float* __restrict__ feat,
                                                const float* __restrict__ tgt,
                                                float* __restrict__ wsS,   // [256][32]
                                                float* __restrict__ wsP) { // [256]
    const int b = blockIdx.x >> 2;      // NSPLIT = 4
    const int slice = blockIdx.x & 3;
    const int tid = threadIdx.x;
    const int lane = tid & 63;
    const int wv = tid >> 6;

    __shared__ float spot_tab[NSPOT][8]; // t0^2,t1^2,t2^2,0, -2t0,-2t1,-2t2,0
    __shared__ float Ssh[4][NSPOT];
    __shared__ float Psh[4];

    // stage per-spot derived values (block-uniform)
    if (tid < NSPOT) {
        const float* tb = tgt + (size_t)b * (NSPOT * 4) + tid * 4;
        float t0 = tb[1], t1 = tb[2], t2 = tb[3];
        spot_tab[tid][0] = t0 * t0;
        spot_tab[tid][1] = t1 * t1;
        spot_tab[tid][2] = t2 * t2;
        spot_tab[tid][3] = 0.f;
        spot_tab[tid][4] = -2.f * t0;
        spot_tab[tid][5] = -2.f * t1;
        spot_tab[tid][6] = -2.f * t2;
        spot_tab[tid][7] = 0.f;
    }
    __syncthreads();

    // ---- load 4 contiguous pixels x 7 planes (float4, coalesced) ----
    const float* fb = feat + (size_t)b * (7 * HW) + slice * PXB;
    const int p4 = tid * 4;

    float4 f0 = *(const float4*)(fb + 0 * HW + p4);
    float4 f1 = *(const float4*)(fb + 1 * HW + p4);
    float4 f2 = *(const float4*)(fb + 2 * HW + p4);
    float4 f3 = *(const float4*)(fb + 3 * HW + p4);
    float4 f4v = *(const float4*)(fb + 4 * HW + p4);
    float4 f5 = *(const float4*)(fb + 5 * HW + p4);
    float4 f6 = *(const float4*)(fb + 6 * HW + p4);

    float pr[PXT] = {f0.x, f0.y, f0.z, f0.w};
    float mu[NG][PXT] = {{f1.x, f1.y, f1.z, f1.w},
                         {f2.x, f2.y, f2.z, f2.w},
                         {f3.x, f3.y, f3.z, f3.w}};
    float sg[NG][PXT] = {{f4v.x, f4v.y, f4v.z, f4v.w},
                         {f5.x, f5.y, f5.z, f5.w},
                         {f6.x, f6.y, f6.z, f6.w}};

    // ---- per-pixel derived coefficients ----
    float A[NG][PXT], Bc[NG][PXT], C[PXT];
    float psum = 0.f;
#pragma unroll
    for (int k = 0; k < PXT; ++k) {
        float p = fmaxf(pr[k], 1e-20f);
        psum += p;
        float c2 = __builtin_amdgcn_logf(p); // log2
#pragma unroll
        for (int g = 0; g < NG; ++g) {
            float s = fmaxf(sg[g][k], 1e-10f);
            c2 -= __builtin_amdgcn_logf(s);
            float nis = -HALF_LOG2E * __builtin_amdgcn_rcpf(s * s);
            float m = mu[g][k];
            A[g][k] = nis;
            Bc[g][k] = m * nis;
            c2 = fmaf(m * m, nis, c2);
        }
        C[k] = c2;
    }

    // ---- main loop: 32 spots x 4 pixels, 6 FMA + exp2 each ----
#pragma unroll
    for (int s = 0; s < NSPOT; ++s) {
        float4 tsq = *(const float4*)&spot_tab[s][0];
        float4 tq = *(const float4*)&spot_tab[s][4];
        float acc = 0.f;
#pragma unroll
        for (int k = 0; k < PXT; ++k) {
            float x = C[k];
            x = fmaf(tsq.x, A[0][k], x);
            x = fmaf(tsq.y, A[1][k], x);
            x = fmaf(tsq.z, A[2][k], x);
            x = fmaf(tq.x, Bc[0][k], x);
            x = fmaf(tq.y, Bc[1][k], x);
            x = fmaf(tq.z, Bc[2][k], x);
            acc += __builtin_amdgcn_exp2f(x);
        }
        float r = wave_reduce_sum(acc);
        if (lane == 0) Ssh[wv][s] = r;
    }
    float rp = wave_reduce_sum(psum);
    if (lane == 0) Psh[wv] = rp;
    __syncthreads();

    if (tid < NSPOT) {
        float tot = Ssh[0][tid] + Ssh[1][tid] + Ssh[2][tid] + Ssh[3][tid];
        atomicAdd(&wsS[b * NSPOT + tid], tot);
    }
    if (tid == 0) {
        atomicAdd(&wsP[b], Psh[0] + Psh[1] + Psh[2] + Psh[3]);
    }
}

__global__ __launch_bounds__(64) void gmm_final(const float* __restrict__ tgt,
                                                const float* __restrict__ wsS,
                                                const float* __restrict__ wsP,
                                                float* __restrict__ out) {
    int b = blockIdx.x * blockDim.x + threadIdx.x;
    if (b >= 256) return;
    float lp = __builtin_amdgcn_logf(wsP[b]) * LN2; // ln(sum p)
    float acc = 0.f;
#pragma unroll 4
    for (int s = 0; s < NSPOT; ++s) {
        float mask = tgt[(size_t)b * 128 + s * 4];
        float ls = __builtin_amdgcn_logf(wsS[b * NSPOT + s]) * LN2; // ln(S)
        acc = fmaf(mask, ls - lp, acc);
    }
    out[b] = -acc;
}

extern "C" void kernel_launch(void* const* d_in, const int* in_sizes, int n_in,
                              void* d_out, int out_size, void* d_ws, size_t ws_size,
                              hipStream_t stream) {
    const float* feat = (const float*)d_in[0];
    const float* tgt = (const float*)d_in[1];
    float* out = (float*)d_out;

    float* wsS = (float*)d_ws;            // 256*32 floats
    float* wsP = wsS + 256 * NSPOT;       // 256 floats

    hipMemsetAsync(d_ws, 0, (256 * NSPOT + 256) * sizeof(float), stream);

    gmm_main<<<256 * NSPLIT, TPB, 0, stream>>>(feat, tgt, wsS, wsP);
    gmm_final<<<4, 64, 0, stream>>>(tgt, wsS, wsP, out);
}

// Round 3
// 82.941 us; speedup vs baseline: 1.0869x; 1.0869x over previous
//
#include <hip/hip_runtime.h>

#define NG 3
#define HW 4096
#define NB 256
#define NSPOT 32
#define NSPLIT 4
#define PXB (HW / NSPLIT)   // 1024 pixels per block
#define TPB 256
#define PXT (PXB / TPB)     // 4 pixels per thread
#define NPAIR (PXT / 2)     // 2 float2 pairs per thread
#define NWAVE (TPB / 64)

// -log2(e)/2
#define NHALF_LOG2E -0.7213475204444817f
#define LN2 0.6931471805599453f

typedef float f32x2 __attribute__((ext_vector_type(2)));

__global__ __launch_bounds__(TPB) void gmm_main(const float* __restrict__ feat,
                                                const float* __restrict__ tgt,
                                                float* __restrict__ wsS,   // [NB][NSPLIT][NSPOT]
                                                float* __restrict__ wsP) { // [NB][NSPLIT]
    const int b = blockIdx.x >> 2;      // NSPLIT = 4
    const int slice = blockIdx.x & 3;
    const int tid = threadIdx.x;
    const int lane = tid & 63;
    const int wv = tid >> 6;

    __shared__ float4 spot_tab[NSPOT];       // t0, t1, t2, 0
    __shared__ float Ssh[NWAVE][NSPOT];
    __shared__ float Psh[NWAVE];

    if (tid < NSPOT) {
        const float* tb = tgt + (size_t)b * (NSPOT * 4) + tid * 4;
        spot_tab[tid] = make_float4(tb[1], tb[2], tb[3], 0.f);
    }
    __syncthreads();

    // ---- load 4 contiguous pixels x 7 planes (float4, coalesced) ----
    const float* fb = feat + (size_t)b * (7 * HW) + slice * PXB;
    const int p4 = tid * 4;

    float4 f0 = *(const float4*)(fb + 0 * HW + p4);
    float4 f1 = *(const float4*)(fb + 1 * HW + p4);
    float4 f2 = *(const float4*)(fb + 2 * HW + p4);
    float4 f3 = *(const float4*)(fb + 3 * HW + p4);
    float4 f4v = *(const float4*)(fb + 4 * HW + p4);
    float4 f5 = *(const float4*)(fb + 5 * HW + p4);
    float4 f6 = *(const float4*)(fb + 6 * HW + p4);

    float pr[PXT] = {f0.x, f0.y, f0.z, f0.w};
    float mu_s[NG][PXT] = {{f1.x, f1.y, f1.z, f1.w},
                           {f2.x, f2.y, f2.z, f2.w},
                           {f3.x, f3.y, f3.z, f3.w}};
    float sg_s[NG][PXT] = {{f4v.x, f4v.y, f4v.z, f4v.w},
                           {f5.x, f5.y, f5.z, f5.w},
                           {f6.x, f6.y, f6.z, f6.w}};

    // ---- per-pixel derived coefficients (numerically stable form) ----
    // a_g = -log2e/(2 sigma_g^2);  C' = log2 p - sum_g log2 sigma_g
    // x(t) = C' + sum_g (z_g * a_g) * z_g,  z_g = t_g - mu_g   (all spot terms <= 0)
    float a_s[NG][PXT], c_s[PXT];
    float psum = 0.f;
#pragma unroll
    for (int k = 0; k < PXT; ++k) {
        float p = fmaxf(pr[k], 1e-20f);
        psum += p;
        float c2 = __builtin_amdgcn_logf(p); // log2
#pragma unroll
        for (int g = 0; g < NG; ++g) {
            float s = fmaxf(sg_s[g][k], 1e-10f);
            c2 -= __builtin_amdgcn_logf(s);
            a_s[g][k] = NHALF_LOG2E * __builtin_amdgcn_rcpf(s * s);
        }
        c_s[k] = c2;
    }

    // pack into float2 pairs to encourage v_pk_* f32 packed math
    f32x2 MU[NG][NPAIR], A[NG][NPAIR], C[NPAIR];
#pragma unroll
    for (int pp = 0; pp < NPAIR; ++pp) {
        C[pp] = (f32x2){c_s[2 * pp], c_s[2 * pp + 1]};
#pragma unroll
        for (int g = 0; g < NG; ++g) {
            MU[g][pp] = (f32x2){mu_s[g][2 * pp], mu_s[g][2 * pp + 1]};
            A[g][pp] = (f32x2){a_s[g][2 * pp], a_s[g][2 * pp + 1]};
        }
    }

    // ---- main loop: 32 spots x 2 pixel-pairs; stable quadratic + exp2 ----
    float acc[NSPOT];
#pragma unroll
    for (int s = 0; s < NSPOT; ++s) {
        float4 t = spot_tab[s];
        f32x2 x[NPAIR];
#pragma unroll
        for (int pp = 0; pp < NPAIR; ++pp) {
            f32x2 x2 = C[pp];
            {
                f32x2 z = t.x - MU[0][pp];
                x2 += (z * A[0][pp]) * z;
            }
            {
                f32x2 z = t.y - MU[1][pp];
                x2 += (z * A[1][pp]) * z;
            }
            {
                f32x2 z = t.z - MU[2][pp];
                x2 += (z * A[2][pp]) * z;
            }
            x[pp] = x2;
        }
        float e0 = __builtin_amdgcn_exp2f(x[0].x) + __builtin_amdgcn_exp2f(x[0].y);
        float e1 = __builtin_amdgcn_exp2f(x[1].x) + __builtin_amdgcn_exp2f(x[1].y);
        acc[s] = e0 + e1;
    }

    // ---- multi-value wave reduction: 32 values across 64 lanes ----
#define RSTEP(D, HALF)                                          \
    {                                                           \
        const bool hi = (lane & (D)) != 0;                      \
        _Pragma("unroll") for (int i = 0; i < (HALF); ++i) {    \
            float send = hi ? acc[i] : acc[i + (HALF)];         \
            float recv = __shfl_xor(send, (D), 64);             \
            acc[i] = (hi ? acc[i + (HALF)] : acc[i]) + recv;    \
        }                                                       \
    }
    RSTEP(32, 16)
    RSTEP(16, 8)
    RSTEP(8, 4)
    RSTEP(4, 2)
    RSTEP(2, 1)
#undef RSTEP
    acc[0] += __shfl_xor(acc[0], 1, 64);
    if ((lane & 1) == 0) Ssh[wv][lane >> 1] = acc[0];

    float ps = psum;
#pragma unroll
    for (int m = 1; m < 64; m <<= 1) ps += __shfl_xor(ps, m, 64);
    if (lane == 0) Psh[wv] = ps;
    __syncthreads();

    if (tid < NSPOT) {
        float tot = 0.f;
#pragma unroll
        for (int w = 0; w < NWAVE; ++w) tot += Ssh[w][tid];
        wsS[((size_t)b * NSPLIT + slice) * NSPOT + tid] = tot;
    }
    if (tid == NSPOT) {
        float tot = 0.f;
#pragma unroll
        for (int w = 0; w < NWAVE; ++w) tot += Psh[w];
        wsP[b * NSPLIT + slice] = tot;
    }
}

__global__ __launch_bounds__(64) void gmm_final(const float* __restrict__ tgt,
                                                const float* __restrict__ wsS,
                                                const float* __restrict__ wsP,
                                                float* __restrict__ out) {
    const int b = blockIdx.x;
    const int lane = threadIdx.x;

    float ps = (lane < NSPLIT) ? wsP[b * NSPLIT + lane] : 0.f;
#pragma unroll
    for (int m = 1; m < 64; m <<= 1) ps += __shfl_xor(ps, m, 64);
    // all lanes now hold total sum(p) for batch b

    float contrib = 0.f;
    if (lane < NSPOT) {
        float S = 0.f;
#pragma unroll
        for (int k = 0; k < NSPLIT; ++k)
            S += wsS[((size_t)b * NSPLIT + k) * NSPOT + lane];
        float mask = tgt[(size_t)b * (NSPOT * 4) + lane * 4];
        contrib = mask * (__builtin_amdgcn_logf(S) - __builtin_amdgcn_logf(ps));
    }
#pragma unroll
    for (int m = 1; m < 64; m <<= 1) contrib += __shfl_xor(contrib, m, 64);

    if (lane == 0) out[b] = -contrib * LN2;
}

extern "C" void kernel_launch(void* const* d_in, const int* in_sizes, int n_in,
                              void* d_out, int out_size, void* d_ws, size_t ws_size,
                              hipStream_t stream) {
    const float* feat = (const float*)d_in[0];
    const float* tgt = (const float*)d_in[1];
    float* out = (float*)d_out;

    float* wsS = (float*)d_ws;                 // NB*NSPLIT*NSPOT floats
    float* wsP = wsS + NB * NSPLIT * NSPOT;    // NB*NSPLIT floats

    gmm_main<<<NB * NSPLIT, TPB, 0, stream>>>(feat, tgt, wsS, wsP);
    gmm_final<<<NB, 64, 0, stream>>>(tgt, wsS, wsP, out);
}

// Round 6
// 80.523 us; speedup vs baseline: 1.1196x; 1.0300x over previous
//
#include <hip/hip_runtime.h>

#define NG 3
#define HW 4096
#define NB 256
#define NSPOT 32
#define TPB 1024
#define PXT 4               // pixels per thread (1024*4 = 4096)
#define NPAIR (PXT / 2)
#define NWAVE (TPB / 64)    // 16

// -log2(e)/2
#define NHALF_LOG2E -0.7213475204444817f
#define LN2 0.6931471805599453f

typedef float f32x2 __attribute__((ext_vector_type(2)));

__global__ __launch_bounds__(TPB) void gmm_fused(const float* __restrict__ feat,
                                                 const float* __restrict__ tgt,
                                                 float* __restrict__ out) {
    const int b = blockIdx.x;
    const int tid = threadIdx.x;
    const int lane = tid & 63;
    const int wv = tid >> 6;

    __shared__ float4 spot_tab[NSPOT];   // t0, t1, t2, 0
    __shared__ float Ssh[NWAVE][NSPOT];
    __shared__ float Psh[NWAVE];

    if (tid < NSPOT) {
        const float* tb = tgt + (size_t)b * (NSPOT * 4) + tid * 4;
        spot_tab[tid] = make_float4(tb[1], tb[2], tb[3], 0.f);
    }
    __syncthreads();

    // ---- load 4 contiguous pixels x 7 planes (float4, coalesced) ----
    const float* fb = feat + (size_t)b * (7 * HW);
    const int p4 = tid * 4;

    float4 f0 = *(const float4*)(fb + 0 * HW + p4);
    float4 f1 = *(const float4*)(fb + 1 * HW + p4);
    float4 f2 = *(const float4*)(fb + 2 * HW + p4);
    float4 f3 = *(const float4*)(fb + 3 * HW + p4);
    float4 f4v = *(const float4*)(fb + 4 * HW + p4);
    float4 f5 = *(const float4*)(fb + 5 * HW + p4);
    float4 f6 = *(const float4*)(fb + 6 * HW + p4);

    float pr[PXT] = {f0.x, f0.y, f0.z, f0.w};
    float mu_s[NG][PXT] = {{f1.x, f1.y, f1.z, f1.w},
                           {f2.x, f2.y, f2.z, f2.w},
                           {f3.x, f3.y, f3.z, f3.w}};
    float sg_s[NG][PXT] = {{f4v.x, f4v.y, f4v.z, f4v.w},
                           {f5.x, f5.y, f5.z, f5.w},
                           {f6.x, f6.y, f6.z, f6.w}};

    // ---- per-pixel derived coefficients (numerically stable form) ----
    // a_g = -log2e/(2 sigma_g^2);  C' = log2 p - sum_g log2 sigma_g
    // x(t) = C' + sum_g (z_g * a_g) * z_g,  z_g = t_g - mu_g  (spot terms <= 0)
    float a_s[NG][PXT], c_s[PXT];
    float psum = 0.f;
#pragma unroll
    for (int k = 0; k < PXT; ++k) {
        float p = fmaxf(pr[k], 1e-20f);
        psum += p;
        float c2 = __builtin_amdgcn_logf(p); // log2
#pragma unroll
        for (int g = 0; g < NG; ++g) {
            float s = fmaxf(sg_s[g][k], 1e-10f);
            c2 -= __builtin_amdgcn_logf(s);
            a_s[g][k] = NHALF_LOG2E * __builtin_amdgcn_rcpf(s * s);
        }
        c_s[k] = c2;
    }

    // pack into float2 pairs for packed f32 math
    f32x2 MU[NG][NPAIR], A[NG][NPAIR], C[NPAIR];
#pragma unroll
    for (int pp = 0; pp < NPAIR; ++pp) {
        C[pp] = (f32x2){c_s[2 * pp], c_s[2 * pp + 1]};
#pragma unroll
        for (int g = 0; g < NG; ++g) {
            MU[g][pp] = (f32x2){mu_s[g][2 * pp], mu_s[g][2 * pp + 1]};
            A[g][pp] = (f32x2){a_s[g][2 * pp], a_s[g][2 * pp + 1]};
        }
    }

    // ---- main loop: 32 spots x 2 pixel-pairs; stable quadratic + exp2 ----
    float acc[NSPOT];
#pragma unroll
    for (int s = 0; s < NSPOT; ++s) {
        float4 t = spot_tab[s];
        f32x2 x[NPAIR];
#pragma unroll
        for (int pp = 0; pp < NPAIR; ++pp) {
            f32x2 x2 = C[pp];
            {
                f32x2 z = t.x - MU[0][pp];
                x2 += (z * A[0][pp]) * z;
            }
            {
                f32x2 z = t.y - MU[1][pp];
                x2 += (z * A[1][pp]) * z;
            }
            {
                f32x2 z = t.z - MU[2][pp];
                x2 += (z * A[2][pp]) * z;
            }
            x[pp] = x2;
        }
        float e0 = __builtin_amdgcn_exp2f(x[0].x) + __builtin_amdgcn_exp2f(x[0].y);
        float e1 = __builtin_amdgcn_exp2f(x[1].x) + __builtin_amdgcn_exp2f(x[1].y);
        acc[s] = e0 + e1;
    }

    // ---- multi-value wave reduction: 32 values across 64 lanes ----
#define RSTEP(D, HALF)                                          \
    {                                                           \
        const bool hi = (lane & (D)) != 0;                      \
        _Pragma("unroll") for (int i = 0; i < (HALF); ++i) {    \
            float send = hi ? acc[i] : acc[i + (HALF)];         \
            float recv = __shfl_xor(send, (D), 64);             \
            acc[i] = (hi ? acc[i + (HALF)] : acc[i]) + recv;    \
        }                                                       \
    }
    RSTEP(32, 16)
    RSTEP(16, 8)
    RSTEP(8, 4)
    RSTEP(4, 2)
    RSTEP(2, 1)
#undef RSTEP
    acc[0] += __shfl_xor(acc[0], 1, 64);
    if ((lane & 1) == 0) Ssh[wv][lane >> 1] = acc[0];

    float ps = psum;
#pragma unroll
    for (int m = 1; m < 64; m <<= 1) ps += __shfl_xor(ps, m, 64);
    if (lane == 0) Psh[wv] = ps;
    __syncthreads();

    // ---- final block reduction on wave 0 ----
    if (tid < 64) {
        float contrib = 0.f, msum = 0.f;
        if (tid < NSPOT) {
            float S = 0.f;
#pragma unroll
            for (int w = 0; w < NWAVE; ++w) S += Ssh[w][tid];
            float mask = tgt[(size_t)b * (NSPOT * 4) + tid * 4];
            contrib = mask * __builtin_amdgcn_logf(S);  // mask * log2(S)
            msum = mask;
        }
        float pv = (tid < NWAVE) ? Psh[tid] : 0.f;
#pragma unroll
        for (int m = 1; m < 64; m <<= 1) {
            contrib += __shfl_xor(contrib, m, 64);
            msum += __shfl_xor(msum, m, 64);
            pv += __shfl_xor(pv, m, 64);
        }
        if (tid == 0)
            out[b] = -LN2 * (contrib - msum * __builtin_amdgcn_logf(pv));
    }
}

extern "C" void kernel_launch(void* const* d_in, const int* in_sizes, int n_in,
                              void* d_out, int out_size, void* d_ws, size_t ws_size,
                              hipStream_t stream) {
    const float* feat = (const float*)d_in[0];
    const float* tgt = (const float*)d_in[1];
    float* out = (float*)d_out;

    gmm_fused<<<NB, TPB, 0, stream>>>(feat, tgt, out);
}

// Round 7
// 78.846 us; speedup vs baseline: 1.1434x; 1.0213x over previous
//
#include <hip/hip_runtime.h>

#define NG 3
#define HW 4096
#define NB 256
#define NSPOT 32
#define TPB 1024
#define PXT 4               // pixels per thread (1024*4 = 4096)
#define NPAIR (PXT / 2)
#define NWAVE (TPB / 64)    // 16

// -log2(e)/2
#define NHALF_LOG2E -0.7213475204444817f
#define LN2 0.6931471805599453f

typedef float f32x2 __attribute__((ext_vector_type(2)));

__global__ __launch_bounds__(TPB) void gmm_fused(const float* __restrict__ feat,
                                                 const float* __restrict__ tgt,
                                                 float* __restrict__ out) {
    const int b = blockIdx.x;
    const int tid = threadIdx.x;
    const int lane = tid & 63;
    const int wv = tid >> 6;

    __shared__ float Ssh[NWAVE][NSPOT];
    __shared__ float Psh[NWAVE];

    // block-uniform spot table base -> scalar (SGPR) loads, no LDS staging
    const float* __restrict__ tb = tgt + (size_t)b * (NSPOT * 4);

    // ---- load 4 contiguous pixels x 7 planes (float4, coalesced) ----
    const float* fb = feat + (size_t)b * (7 * HW);
    const int p4 = tid * 4;

    float4 f0 = *(const float4*)(fb + 0 * HW + p4);
    float4 f1 = *(const float4*)(fb + 1 * HW + p4);
    float4 f2 = *(const float4*)(fb + 2 * HW + p4);
    float4 f3 = *(const float4*)(fb + 3 * HW + p4);
    float4 f4v = *(const float4*)(fb + 4 * HW + p4);
    float4 f5 = *(const float4*)(fb + 5 * HW + p4);
    float4 f6 = *(const float4*)(fb + 6 * HW + p4);

    float pr[PXT] = {f0.x, f0.y, f0.z, f0.w};
    float mu_s[NG][PXT] = {{f1.x, f1.y, f1.z, f1.w},
                           {f2.x, f2.y, f2.z, f2.w},
                           {f3.x, f3.y, f3.z, f3.w}};
    float sg_s[NG][PXT] = {{f4v.x, f4v.y, f4v.z, f4v.w},
                           {f5.x, f5.y, f5.z, f5.w},
                           {f6.x, f6.y, f6.z, f6.w}};

    // ---- per-pixel derived coefficients (numerically stable form) ----
    // a_g = -log2e/(2 sigma_g^2)
    // C'  = log2 p - log2(sigma0*sigma1*sigma2)   (product in [1e-30, ~1])
    // x(t) = C' + sum_g (z_g * a_g) * z_g,  z_g = t_g - mu_g  (spot terms <= 0)
    float a_s[NG][PXT], c_s[PXT];
    float psum = 0.f;
#pragma unroll
    for (int k = 0; k < PXT; ++k) {
        float p = fmaxf(pr[k], 1e-20f);
        psum += p;
        float prod = 1.f;
#pragma unroll
        for (int g = 0; g < NG; ++g) {
            float s = fmaxf(sg_s[g][k], 1e-10f);
            prod *= s;
            a_s[g][k] = NHALF_LOG2E * __builtin_amdgcn_rcpf(s * s);
        }
        c_s[k] = __builtin_amdgcn_logf(p) - __builtin_amdgcn_logf(prod);
    }

    // pack into float2 pairs for packed f32 math
    f32x2 MU[NG][NPAIR], A[NG][NPAIR], C[NPAIR];
#pragma unroll
    for (int pp = 0; pp < NPAIR; ++pp) {
        C[pp] = (f32x2){c_s[2 * pp], c_s[2 * pp + 1]};
#pragma unroll
        for (int g = 0; g < NG; ++g) {
            MU[g][pp] = (f32x2){mu_s[g][2 * pp], mu_s[g][2 * pp + 1]};
            A[g][pp] = (f32x2){a_s[g][2 * pp], a_s[g][2 * pp + 1]};
        }
    }

    // ---- main loop: 32 spots x 2 pixel-pairs; stable quadratic + exp2 ----
    float acc[NSPOT];
#pragma unroll
    for (int s = 0; s < NSPOT; ++s) {
        const float tx = tb[4 * s + 1];   // uniform -> SGPR
        const float ty = tb[4 * s + 2];
        const float tz = tb[4 * s + 3];
        f32x2 x[NPAIR];
#pragma unroll
        for (int pp = 0; pp < NPAIR; ++pp) {
            f32x2 x2 = C[pp];
            {
                f32x2 z = tx - MU[0][pp];
                x2 += (z * A[0][pp]) * z;
            }
            {
                f32x2 z = ty - MU[1][pp];
                x2 += (z * A[1][pp]) * z;
            }
            {
                f32x2 z = tz - MU[2][pp];
                x2 += (z * A[2][pp]) * z;
            }
            x[pp] = x2;
        }
        float e0 = __builtin_amdgcn_exp2f(x[0].x) + __builtin_amdgcn_exp2f(x[0].y);
        float e1 = __builtin_amdgcn_exp2f(x[1].x) + __builtin_amdgcn_exp2f(x[1].y);
        acc[s] = e0 + e1;
    }

    // ---- multi-value wave reduction: 32 values across 64 lanes ----
#define RSTEP(D, HALF)                                          \
    {                                                           \
        const bool hi = (lane & (D)) != 0;                      \
        _Pragma("unroll") for (int i = 0; i < (HALF); ++i) {    \
            float send = hi ? acc[i] : acc[i + (HALF)];         \
            float recv = __shfl_xor(send, (D), 64);             \
            acc[i] = (hi ? acc[i + (HALF)] : acc[i]) + recv;    \
        }                                                       \
    }
    RSTEP(32, 16)
    RSTEP(16, 8)
    RSTEP(8, 4)
    RSTEP(4, 2)
    RSTEP(2, 1)
#undef RSTEP
    acc[0] += __shfl_xor(acc[0], 1, 64);
    if ((lane & 1) == 0) Ssh[wv][lane >> 1] = acc[0];

    float ps = psum;
#pragma unroll
    for (int m = 1; m < 64; m <<= 1) ps += __shfl_xor(ps, m, 64);
    if (lane == 0) Psh[wv] = ps;
    __syncthreads();

    // ---- final block reduction on wave 0 ----
    if (tid < 64) {
        float contrib = 0.f, msum = 0.f;
        if (tid < NSPOT) {
            float S = 0.f;
#pragma unroll
            for (int w = 0; w < NWAVE; ++w) S += Ssh[w][tid];
            float mask = tgt[(size_t)b * (NSPOT * 4) + tid * 4];
            contrib = mask * __builtin_amdgcn_logf(S);  // mask * log2(S)
            msum = mask;
        }
        float pv = (tid < NWAVE) ? Psh[tid] : 0.f;
#pragma unroll
        for (int m = 1; m < 64; m <<= 1) {
            contrib += __shfl_xor(contrib, m, 64);
            msum += __shfl_xor(msum, m, 64);
            pv += __shfl_xor(pv, m, 64);
        }
        if (tid == 0)
            out[b] = -LN2 * (contrib - msum * __builtin_amdgcn_logf(pv));
    }
}

extern "C" void kernel_launch(void* const* d_in, const int* in_sizes, int n_in,
                              void* d_out, int out_size, void* d_ws, size_t ws_size,
                              hipStream_t stream) {
    const float* feat = (const float*)d_in[0];
    const float* tgt = (const float*)d_in[1];
    float* out = (float*)d_out;

    gmm_fused<<<NB, TPB, 0, stream>>>(feat, tgt, out);
}